// Round 9
// baseline (377.866 us; speedup 1.0000x reference)
//
#include <hip/hip_runtime.h>
#include <cstdint>

// B=4 per input, H=W=64, N=4096 px, C3=256. Output (4,512,64,64) fp32.
#define NPX 4096

using bf16x8 = __attribute__((ext_vector_type(8))) short;
using f32x4  = __attribute__((ext_vector_type(4))) float;

__device__ inline unsigned short f2bf_rne(float x) {
    unsigned u = __float_as_uint(x);
    unsigned r = (u + 0x7fffu + ((u >> 16) & 1u)) >> 16;
    return (unsigned short)r;
}
__device__ inline float bf2f(unsigned short h) {
    return __uint_as_float(((unsigned)h) << 16);
}

#define GLL(gp, lp) __builtin_amdgcn_global_load_lds( \
    (const __attribute__((address_space(1))) void*)(gp), \
    (__attribute__((address_space(3))) void*)(lp), 16, 0, 0)

// ---------------------------------------------------------------------------
// conv1: 1 -> 32 channels, direct.
// ---------------------------------------------------------------------------
__global__ __launch_bounds__(256) void conv1_k(
    const float* __restrict__ x1, const float* __restrict__ x2,
    const float* __restrict__ w,  const float* __restrict__ bias,
    float* __restrict__ y1)
{
    int gid = blockIdx.x * 256 + threadIdx.x;
    int px  = gid & 4095;
    int co  = (gid >> 12) & 31;
    int img = gid >> 17;
    const float* xin = (img < 4) ? (x1 + (size_t)img * NPX)
                                 : (x2 + (size_t)(img - 4) * NPX);
    int r = px >> 6, c = px & 63;
    float acc = bias[co];
#pragma unroll
    for (int dy = 0; dy < 3; ++dy) {
        int rr = r + dy - 1;
        if (rr < 0 || rr > 63) continue;
#pragma unroll
        for (int dx = 0; dx < 3; ++dx) {
            int cc = c + dx - 1;
            if (cc < 0 || cc > 63) continue;
            acc = fmaf(w[co * 9 + dy * 3 + dx], xin[rr * 64 + cc], acc);
        }
    }
    y1[(size_t)img * 32 * NPX + (size_t)co * NPX + px] = acc;
}

// ---------------------------------------------------------------------------
// wtrans: wT[(ci*9+tap)*CO + co] = w[co][ci][tap]  (conv2 only)
// ---------------------------------------------------------------------------
__global__ __launch_bounds__(256) void wtrans_k(
    const float* __restrict__ w, float* __restrict__ wT,
    int CI9, int CO, int total)
{
    int gid = blockIdx.x * 256 + threadIdx.x;
    if (gid >= total) return;
    int k = gid / CO, co = gid - k * CO;
    wT[gid] = w[(size_t)co * CI9 + k];
}

// ---------------------------------------------------------------------------
// convg: conv2 (32->64), register-tile implicit GEMM (proven round 3).
// ---------------------------------------------------------------------------
template <int CI>
__global__ __launch_bounds__(256) void convg_k(
    const float* __restrict__ in,
    const float* __restrict__ wT,
    const float* __restrict__ bias,
    float* __restrict__ outA, float* __restrict__ outB,
    int strideA, int strideB, int COT)
{
    constexpr int CIC = 16;
    __shared__ __align__(16) float in_lds[CIC * 6 * 64];
    __shared__ __align__(16) float w_lds[CIC * 9 * 64];

    const int r0  = blockIdx.x * 4;
    const int img = blockIdx.y;
    const int cob = blockIdx.z * 64;
    const int tid = threadIdx.x;
    const int co4 = (tid & 15) * 4;
    const int pxg = tid >> 4;
    const int row_l = pxg >> 2;
    const int c0 = (pxg & 3) * 16;

    const float* ib = in + (size_t)img * CI * NPX;

    float acc[4][16];
#pragma unroll
    for (int e = 0; e < 4; ++e) {
        float bv = bias[cob + co4 + e];
#pragma unroll
        for (int p = 0; p < 16; ++p) acc[e][p] = bv;
    }

    for (int cic = 0; cic < CI; cic += CIC) {
        __syncthreads();
#pragma unroll
        for (int t = 0; t < 6; ++t) {
            int f = tid + t * 256;
            int ci = f / 96, rem = f - ci * 96;
            int dyr = rem >> 4, c4 = rem & 15;
            int gr = r0 + dyr - 1;
            float4 v = make_float4(0.f, 0.f, 0.f, 0.f);
            if (gr >= 0 && gr < 64)
                v = *(const float4*)&ib[(size_t)(cic + ci) * NPX + gr * 64 + c4 * 4];
            *(float4*)&in_lds[(ci * 6 + dyr) * 64 + c4 * 4] = v;
        }
#pragma unroll
        for (int t = 0; t < 9; ++t) {
            int f = tid + t * 256;
            int k = f >> 4, c4 = f & 15;
            *(float4*)&w_lds[k * 64 + c4 * 4] =
                *(const float4*)&wT[(size_t)(cic * 9 + k) * COT + cob + c4 * 4];
        }
        __syncthreads();

        for (int ci = 0; ci < CIC; ++ci) {
#pragma unroll
            for (int dy = 0; dy < 3; ++dy) {
                const float* rp = &in_lds[(ci * 6 + row_l + dy) * 64 + c0];
                float v[18];
                float left  = rp[(c0 == 0)  ? 0 : -1];
                float right = rp[(c0 == 48) ? 0 : 16];
                v[0]  = (c0 == 0)  ? 0.f : left;
                *(float4*)&v[1]  = *(const float4*)&rp[0];
                *(float4*)&v[5]  = *(const float4*)&rp[4];
                *(float4*)&v[9]  = *(const float4*)&rp[8];
                *(float4*)&v[13] = *(const float4*)&rp[12];
                v[17] = (c0 == 48) ? 0.f : right;
                const float* wp = &w_lds[(ci * 9 + dy * 3) * 64 + co4];
                float wv[3][4];
                *(float4*)&wv[0][0] = *(const float4*)&wp[0];
                *(float4*)&wv[1][0] = *(const float4*)&wp[64];
                *(float4*)&wv[2][0] = *(const float4*)&wp[128];
#pragma unroll
                for (int dx = 0; dx < 3; ++dx)
#pragma unroll
                    for (int e = 0; e < 4; ++e)
#pragma unroll
                        for (int p = 0; p < 16; ++p)
                            acc[e][p] = fmaf(wv[dx][e], v[p + dx], acc[e][p]);
            }
        }
    }

    float* dst = (img < 4) ? (outA + (size_t)img * strideA)
                           : (outB + (size_t)(img - 4) * strideB);
    dst += (size_t)(cob + co4) * NPX + (r0 + row_l) * 64 + c0;
#pragma unroll
    for (int e = 0; e < 4; ++e)
#pragma unroll
        for (int q = 0; q < 4; ++q)
            *(float4*)&dst[(size_t)e * NPX + q * 4] = *(float4*)&acc[e][q * 4];
}

// ---------------------------------------------------------------------------
// wprep: w3 [256co][64ci][9tap] -> frag-contiguous bf16 h/l buffer.
// ---------------------------------------------------------------------------
__global__ __launch_bounds__(256) void wprep_k(
    const float* __restrict__ w3, unsigned short* __restrict__ w3f)
{
    int i = blockIdx.x * 256 + threadIdx.x;
    if (i >= 147456) return;
    int tap = i % 9;  int t2 = i / 9;
    int ci = t2 & 63; int co = t2 >> 6;
    float v = w3[(size_t)(co * 64 + ci) * 9 + tap];
    unsigned short hi = f2bf_rne(v);
    unsigned short lo = f2bf_rne(v - bf2f(hi));
    int cg = co >> 7, wm = (co >> 6) & 1, mf = (co >> 4) & 3, l15 = co & 15;
    int ch = ci >> 5, q = (ci >> 3) & 3, e = ci & 7;
    int lane = q * 16 + l15;
    size_t o = (size_t)(cg * 2 + wm) * 73728 + tap * 8192 + ch * 4096
             + mf * 512 + lane * 8 + e;
    w3f[o] = hi;
    w3f[o + 2048] = lo;
}

// ---------------------------------------------------------------------------
// y2prep: y2 [8][64ci][4096px] fp32 -> h/l [8][66 rows][64px][64ci] bf16.
// ---------------------------------------------------------------------------
__global__ __launch_bounds__(256) void y2prep_k(
    const float* __restrict__ y2,
    unsigned short* __restrict__ h, unsigned short* __restrict__ l)
{
    const int rg = blockIdx.x;   // 0..65
    const int img = blockIdx.y;
    const int tid = threadIdx.x;
    const size_t base = ((size_t)img * 66 + rg) * 4096;
    if (rg == 0 || rg == 65) {
#pragma unroll
        for (int t = 0; t < 16; ++t) {
            h[base + tid + t * 256] = 0;
            l[base + tid + t * 256] = 0;
        }
        return;
    }
    __shared__ float T[64][65];
    const int row = rg - 1;
#pragma unroll
    for (int t = 0; t < 16; ++t) {
        int ii = tid + t * 256;
        int ci = ii >> 6, col = ii & 63;
        T[ci][col] = y2[(size_t)img * 262144 + (size_t)ci * NPX + row * 64 + col];
    }
    __syncthreads();
#pragma unroll
    for (int t = 0; t < 16; ++t) {
        int ii = tid + t * 256;
        int ci = ii & 63, px = ii >> 6;
        float v = T[ci][px];
        unsigned short hi = f2bf_rne(v);
        h[base + px * 64 + ci] = hi;
        l[base + px * 64 + ci] = f2bf_rne(v - bf2f(hi));
    }
}

// ---------------------------------------------------------------------------
// conv3m: conv3 (64->256) as 9-tap shifted MFMA GEMM (proven round 5).
// ---------------------------------------------------------------------------
__global__ __launch_bounds__(512, 2) void conv3m_k(
    const unsigned short* __restrict__ y2ph,
    const unsigned short* __restrict__ y2pl,
    const unsigned short* __restrict__ w3f,
    const float* __restrict__ b3,
    float* __restrict__ out, float* __restrict__ f2)
{
    __shared__ unsigned short xlds[49152];
    const int pxg = blockIdx.x;
    const int img = blockIdx.y;
    const int cg  = blockIdx.z;
    const int tid = threadIdx.x;
    const int lane = tid & 63;
    const int wid = tid >> 6;
    const int wm = wid >> 2, wn = wid & 3;
    const int q16 = lane >> 4, l15 = lane & 15;
    const int r0 = pxg * 4;
    const int px0 = pxg * 256;
    const int cob = cg * 128;

    const unsigned short* yh = y2ph + (size_t)img * 270336;
    const unsigned short* yl = y2pl + (size_t)img * 270336;
#pragma unroll
    for (int it = 0; it < 12; ++it) {
        int dbase = it * 8192 + wid * 1024;
        int d = dbase + lane * 16;
        int s = d >= 49152;
        int r = d - (s ? 49152 : 0);
        int pxl = r >> 7;
        int kbs = (r >> 4) & 7;
        int kb  = kbs ^ (pxl & 7);
        int rg  = r0 + (pxl >> 6);
        int col = pxl & 63;
        const unsigned short* src = (s ? yl : yh) + ((rg << 6) + col) * 64 + kb * 8;
        GLL(src, (char*)xlds + dbase);
    }

    const unsigned short* wbase = w3f + (size_t)(cg * 2 + wm) * 73728 + lane * 8;
    bf16x8 awh[2][4], awl[2][4];
#pragma unroll
    for (int mf = 0; mf < 4; ++mf) {
        awh[0][mf] = *(const bf16x8*)(wbase + mf * 512);
        awl[0][mf] = *(const bf16x8*)(wbase + 2048 + mf * 512);
    }

    f32x4 acc[4][4];
#pragma unroll
    for (int mf = 0; mf < 4; ++mf) {
        float bv[4];
#pragma unroll
        for (int r = 0; r < 4; ++r)
            bv[r] = b3[cob + wm * 64 + mf * 16 + q16 * 4 + r];
#pragma unroll
        for (int nf = 0; nf < 4; ++nf)
#pragma unroll
            for (int r = 0; r < 4; ++r) acc[mf][nf][r] = bv[r];
    }

    const int plb = wn * 64 + 64 + l15;
    const int key_m = (lane + 7) & 7;
    const int key_0 = lane & 7;
    const int key_p = (lane + 1) & 7;
    const bf16x8 z8 = {0, 0, 0, 0, 0, 0, 0, 0};

    __syncthreads();

#pragma unroll
    for (int ch = 0; ch < 2; ++ch) {
#pragma unroll
        for (int tap = 0; tap < 9; ++tap) {
            const int st = ch * 9 + tap;
            const int cur = st & 1;
            if (st < 17) {
                const int nst = st + 1;
                const int nch = nst / 9, ntap = nst % 9;
#pragma unroll
                for (int mf = 0; mf < 4; ++mf) {
                    awh[cur ^ 1][mf] = *(const bf16x8*)(wbase + ntap * 8192 + nch * 4096 + mf * 512);
                    awl[cur ^ 1][mf] = *(const bf16x8*)(wbase + ntap * 8192 + nch * 4096 + 2048 + mf * 512);
                }
            }
            const int dy = tap / 3 - 1, dx = tap % 3 - 1;
            const int key = (dx < 0) ? key_m : ((dx > 0) ? key_p : key_0);
            bf16x8 bh[4], bl[4];
#pragma unroll
            for (int nf = 0; nf < 4; ++nf) {
                int row = plb + nf * 16 + dy * 64 + dx;
                row = row < 0 ? 0 : (row > 383 ? 383 : row);
                int kbs = (q16 + ch * 4) ^ key;
                int ba = row * 128 + kbs * 16;
                bh[nf] = *(const bf16x8*)((const char*)xlds + ba);
                bl[nf] = *(const bf16x8*)((const char*)xlds + ba + 49152);
                if (dx < 0 && nf == 0) {
                    bh[nf] = (l15 == 0) ? z8 : bh[nf];
                    bl[nf] = (l15 == 0) ? z8 : bl[nf];
                }
                if (dx > 0 && nf == 3) {
                    bh[nf] = (l15 == 15) ? z8 : bh[nf];
                    bl[nf] = (l15 == 15) ? z8 : bl[nf];
                }
            }
#pragma unroll
            for (int mf = 0; mf < 4; ++mf)
#pragma unroll
                for (int nf = 0; nf < 4; ++nf) {
                    f32x4 c = acc[mf][nf];
                    c = __builtin_amdgcn_mfma_f32_16x16x32_bf16(awh[cur][mf], bh[nf], c, 0, 0, 0);
                    c = __builtin_amdgcn_mfma_f32_16x16x32_bf16(awh[cur][mf], bl[nf], c, 0, 0, 0);
                    c = __builtin_amdgcn_mfma_f32_16x16x32_bf16(awl[cur][mf], bh[nf], c, 0, 0, 0);
                    acc[mf][nf] = c;
                }
        }
    }

    float* dst = (img < 4) ? out + (size_t)img * 512 * NPX
                           : f2  + (size_t)(img - 4) * 256 * NPX;
#pragma unroll
    for (int mf = 0; mf < 4; ++mf)
#pragma unroll
        for (int nf = 0; nf < 4; ++nf)
#pragma unroll
            for (int r = 0; r < 4; ++r) {
                int co = cob + wm * 64 + mf * 16 + q16 * 4 + r;
                int px = px0 + wn * 64 + nf * 16 + l15;
                dst[(size_t)co * NPX + px] = acc[mf][nf][r];
            }
}

// ---------------------------------------------------------------------------
// splitT: [256k][4096m] fp32 -> [4096m][256k] bf16 hi+lo (LDS transpose).
// ---------------------------------------------------------------------------
__global__ __launch_bounds__(256) void splitT_k(
    const float* __restrict__ src, size_t srcStride,
    unsigned short* __restrict__ dh, unsigned short* __restrict__ dl)
{
    __shared__ float T[64][65];
    const int m0 = blockIdx.x * 64, k0 = blockIdx.y * 64, b = blockIdx.z;
    const float* s = src + (size_t)b * srcStride;
    const int tid = threadIdx.x;
    const int cm = tid & 63, rk = tid >> 6;
#pragma unroll
    for (int t = 0; t < 16; ++t)
        T[rk + t * 4][cm] = s[(size_t)(k0 + rk + t * 4) * NPX + m0 + cm];
    __syncthreads();
    const int ck = tid & 63, rm = tid >> 6;
#pragma unroll
    for (int t = 0; t < 16; ++t) {
        int m = rm + t * 4;
        float v = T[ck][m];
        unsigned short hi = f2bf_rne(v);
        float lo = v - bf2f(hi);
        size_t o = ((size_t)b * NPX + m0 + m) * 256 + k0 + ck;
        dh[o] = hi;
        dl[o] = f2bf_rne(lo);
    }
}

// ---------------------------------------------------------------------------
// normB + minkey init
// ---------------------------------------------------------------------------
__global__ __launch_bounds__(256) void normb_k(
    const float* __restrict__ f2, float* __restrict__ normB,
    unsigned long long* __restrict__ minkey)
{
    int gid = blockIdx.x * 256 + threadIdx.x;
    int b = gid >> 12, j = gid & 4095;
    const float* p = f2 + (size_t)b * 256 * NPX + j;
    float s = 0.f;
#pragma unroll 8
    for (int c = 0; c < 256; ++c) {
        float v = p[(size_t)c * NPX];
        s = fmaf(v, v, s);
    }
    normB[gid] = s;
    minkey[gid] = ~0ull;
}

// ---------------------------------------------------------------------------
// gemm_argmin_mfma: cross = f1.f2^T via 3x bf16-split MFMA (hh+hl+lh; ll
// term ~2^-18 relative, dropped — same scheme proven in conv3m), fused
// dist-key argmin. Tile 128i x 128j, BK=32, 4 waves 2x2.
// T3-min 2-phase: double-buffered LDS (2x32KB); STAGE(next) issued before
// ds_read+MFMA of current; ONE barrier per iter (drains vmcnt late).
// Bank-conflict fix: 16B-slot index XORed with (row>>1)&3 on BOTH the
// global source (staging) and the read offset (rule #21 involution).
// ---------------------------------------------------------------------------
__global__ __launch_bounds__(256) void gemm_argmin_mfma_k(
    const unsigned short* __restrict__ f1h, const unsigned short* __restrict__ f1l,
    const unsigned short* __restrict__ f2h, const unsigned short* __restrict__ f2l,
    const float* __restrict__ normB,
    unsigned long long* __restrict__ minkey)
{
    __shared__ unsigned short lds[2][4][4096];   // [dbuf][Ah|Al|Bh|Bl], 64 KB
    const int b  = blockIdx.z;
    const int i0 = blockIdx.y * 128;
    const int j0 = blockIdx.x * 128;
    const int tid  = threadIdx.x;
    const int lane = tid & 63;
    const int w    = tid >> 6;
    const int wm   = w >> 1, wn = w & 1;

    // staging: wave w covers rows w*32..w*32+31 (and +16 via twin pointer);
    // lane -> row w*32+(lane>>2), 16B slot (lane&3). Source k-chunk is
    // slot ^ key(row), key(row) = (row>>1)&3 = (lane>>3)&3.
    const int srow  = w * 32 + (lane >> 2);
    const int skoff = (((lane & 3) ^ ((lane >> 3) & 3))) * 8;
    const unsigned short* pAh = f1h + ((size_t)b * NPX + i0 + srow) * 256 + skoff;
    const unsigned short* pAl = f1l + ((size_t)b * NPX + i0 + srow) * 256 + skoff;
    const unsigned short* pBh = f2h + ((size_t)b * NPX + j0 + srow) * 256 + skoff;
    const unsigned short* pBl = f2l + ((size_t)b * NPX + j0 + srow) * 256 + skoff;
    const unsigned short* pAh2 = pAh + 16 * 256;
    const unsigned short* pAl2 = pAl + 16 * 256;
    const unsigned short* pBh2 = pBh + 16 * 256;
    const unsigned short* pBl2 = pBl + 16 * 256;

#define STAGE(p) do { \
        GLL(pAh,  &lds[p][0][0] + w * 1024); GLL(pAh2, &lds[p][0][0] + w * 1024 + 512); \
        GLL(pAl,  &lds[p][1][0] + w * 1024); GLL(pAl2, &lds[p][1][0] + w * 1024 + 512); \
        GLL(pBh,  &lds[p][2][0] + w * 1024); GLL(pBh2, &lds[p][2][0] + w * 1024 + 512); \
        GLL(pBl,  &lds[p][3][0] + w * 1024); GLL(pBl2, &lds[p][3][0] + w * 1024 + 512); \
        pAh += 32; pAl += 32; pBh += 32; pBl += 32; \
        pAh2 += 32; pAl2 += 32; pBh2 += 32; pBl2 += 32; } while (0)

    // fragment read offsets (ushort units), swizzled slot
    const int r15 = lane & 15;
    const int swz = (r15 >> 1) & 3;
    const int aoff = (wm * 64 + r15) * 32 + (((lane >> 4) ^ swz)) * 8;
    const int boff = (wn * 64 + r15) * 32 + (((lane >> 4) ^ swz)) * 8;

    const f32x4 zero = {0.f, 0.f, 0.f, 0.f};
    f32x4 acc[4][4];
#pragma unroll
    for (int i = 0; i < 4; ++i)
#pragma unroll
        for (int j = 0; j < 4; ++j) acc[i][j] = zero;

    STAGE(0);
    __syncthreads();

#pragma unroll
    for (int kb = 0; kb < 8; ++kb) {
        const int cur = kb & 1;
        if (kb < 7) STAGE(cur ^ 1);    // issue next-tile loads (overlap)

        bf16x8 ah[4], al[4], bh[4], bl[4];
#pragma unroll
        for (int mf = 0; mf < 4; ++mf) {
            ah[mf] = *(const bf16x8*)&lds[cur][0][aoff + mf * 512];
            al[mf] = *(const bf16x8*)&lds[cur][1][aoff + mf * 512];
        }
#pragma unroll
        for (int nf = 0; nf < 4; ++nf) {
            bh[nf] = *(const bf16x8*)&lds[cur][2][boff + nf * 512];
            bl[nf] = *(const bf16x8*)&lds[cur][3][boff + nf * 512];
        }
#pragma unroll
        for (int mf = 0; mf < 4; ++mf)
#pragma unroll
            for (int nf = 0; nf < 4; ++nf) {
                f32x4 c = acc[mf][nf];
                c = __builtin_amdgcn_mfma_f32_16x16x32_bf16(ah[mf], bh[nf], c, 0, 0, 0);
                c = __builtin_amdgcn_mfma_f32_16x16x32_bf16(ah[mf], bl[nf], c, 0, 0, 0);
                c = __builtin_amdgcn_mfma_f32_16x16x32_bf16(al[mf], bh[nf], c, 0, 0, 0);
                acc[mf][nf] = c;
            }
        __syncthreads();               // next buffer staged + all reads done
    }
#undef STAGE

    // epilogue: key = normB[j] - 2*cross packed with j; reduce over j-lanes
    float nbv[4];
    const float* nbp = normB + b * 4096 + j0 + wn * 64 + r15;
#pragma unroll
    for (int nf = 0; nf < 4; ++nf) nbv[nf] = nbp[nf * 16];
    const int jcol = j0 + wn * 64 + r15;

#pragma unroll
    for (int mf = 0; mf < 4; ++mf) {
#pragma unroll
        for (int reg = 0; reg < 4; ++reg) {
            unsigned long long kmin = ~0ull;
#pragma unroll
            for (int nf = 0; nf < 4; ++nf) {
                float d = fmaf(-2.f, acc[mf][nf][reg], nbv[nf]);
                unsigned u = __float_as_uint(d);
                u = (u & 0x80000000u) ? ~u : (u | 0x80000000u);
                unsigned long long key =
                    ((unsigned long long)u << 32) | (unsigned)(jcol + nf * 16);
                kmin = kmin < key ? kmin : key;
            }
#pragma unroll
            for (int s = 1; s < 16; s <<= 1) {
                unsigned long long o = __shfl_xor(kmin, s, 64);
                kmin = kmin < o ? kmin : o;
            }
            if (r15 == 0) {
                int i = i0 + wm * 64 + mf * 16 + (lane >> 4) * 4 + reg;
                atomicMin(&minkey[(size_t)b * 4096 + i], kmin);
            }
        }
    }
}

// ---------------------------------------------------------------------------
// gather
// ---------------------------------------------------------------------------
__global__ __launch_bounds__(256) void gather_k(
    const unsigned long long* __restrict__ minkey,
    const float* __restrict__ f2, float* __restrict__ out)
{
    int b  = blockIdx.y;
    int px = blockIdx.x * 256 + threadIdx.x;
    int idx = (int)(unsigned)(minkey[(size_t)b * 4096 + px] & 0xffffffffu);
    const float* src = f2 + (size_t)b * 256 * NPX;
    float* dst = out + (size_t)b * 512 * NPX + (size_t)256 * NPX + px;
#pragma unroll 4
    for (int c = 0; c < 256; ++c)
        dst[(size_t)c * NPX] = src[(size_t)c * NPX + idx];
}

// ---------------------------------------------------------------------------
extern "C" void kernel_launch(void* const* d_in, const int* in_sizes, int n_in,
                              void* d_out, int out_size, void* d_ws, size_t ws_size,
                              hipStream_t stream)
{
    const float* x1 = (const float*)d_in[0];
    const float* x2 = (const float*)d_in[1];
    const float* w1 = (const float*)d_in[2];
    const float* b1 = (const float*)d_in[3];
    const float* w2 = (const float*)d_in[4];
    const float* b2 = (const float*)d_in[5];
    const float* w3 = (const float*)d_in[6];
    const float* b3 = (const float*)d_in[7];
    float* out = (float*)d_out;
    char* ws = (char*)d_ws;

    // ws layout (bytes); high-water ~55.7 MB
    float* y1 = (float*)(ws);                               // dead after conv2
    float* y2 = (float*)(ws + 4194304);                     // dead after y2prep
    float* f2 = (float*)(ws + 12582912);                    // live to end
    float* normB = (float*)(ws + 29360128);
    unsigned long long* minkey = (unsigned long long*)(ws + 29425664);
    float* w2T = (float*)(ws + 29556736);
    unsigned short* w3f  = (unsigned short*)(ws + 29630464);   // 576 KB
    unsigned short* y2ph = (unsigned short*)(ws + 30220288);   // dead after conv3
    unsigned short* y2pl = (unsigned short*)(ws + 34545664);   // dead after conv3
    unsigned short* f1h  = (unsigned short*)(ws);              // overlays y1+y2
    unsigned short* f1l  = (unsigned short*)(ws + 30220288);   // overlays y2pre
    unsigned short* f2h  = (unsigned short*)(ws + 38871040);
    unsigned short* f2l  = (unsigned short*)(ws + 47259648);   // ends 55.65M

    wtrans_k<<<72, 256, 0, stream>>>(w2, w2T, 32 * 9, 64, 64 * 288);
    wprep_k<<<576, 256, 0, stream>>>(w3, w3f);

    conv1_k<<<4096, 256, 0, stream>>>(x1, x2, w1, b1, y1);

    convg_k<32><<<dim3(16, 8, 1), 256, 0, stream>>>(
        y1, w2T, b2, y2, y2 + (size_t)4 * 64 * NPX, 64 * NPX, 64 * NPX, 64);

    y2prep_k<<<dim3(66, 8), 256, 0, stream>>>(y2, y2ph, y2pl);

    conv3m_k<<<dim3(16, 8, 2), 512, 0, stream>>>(y2ph, y2pl, w3f, b3, out, f2);

    normb_k<<<64, 256, 0, stream>>>(f2, normB, minkey);

    splitT_k<<<dim3(64, 4, 4), 256, 0, stream>>>(out, (size_t)512 * NPX, f1h, f1l);
    splitT_k<<<dim3(64, 4, 4), 256, 0, stream>>>(f2,  (size_t)256 * NPX, f2h, f2l);

    gemm_argmin_mfma_k<<<dim3(32, 32, 4), 256, 0, stream>>>(
        f1h, f1l, f2h, f2l, normB, minkey);

    gather_k<<<dim3(16, 4), 256, 0, stream>>>(minkey, f2, out);
}

// Round 10
// 361.299 us; speedup vs baseline: 1.0459x; 1.0459x over previous
//
#include <hip/hip_runtime.h>
#include <cstdint>

// B=4 per input, H=W=64, N=4096 px, C3=256. Output (4,512,64,64) fp32.
#define NPX 4096

using bf16x8 = __attribute__((ext_vector_type(8))) short;
using f32x4  = __attribute__((ext_vector_type(4))) float;

__device__ inline unsigned short f2bf_rne(float x) {
    unsigned u = __float_as_uint(x);
    unsigned r = (u + 0x7fffu + ((u >> 16) & 1u)) >> 16;
    return (unsigned short)r;
}
__device__ inline float bf2f(unsigned short h) {
    return __uint_as_float(((unsigned)h) << 16);
}

#define GLL(gp, lp) __builtin_amdgcn_global_load_lds( \
    (const __attribute__((address_space(1))) void*)(gp), \
    (__attribute__((address_space(3))) void*)(lp), 16, 0, 0)

// ---------------------------------------------------------------------------
// conv1: 1 -> 32 channels, direct.
// ---------------------------------------------------------------------------
__global__ __launch_bounds__(256) void conv1_k(
    const float* __restrict__ x1, const float* __restrict__ x2,
    const float* __restrict__ w,  const float* __restrict__ bias,
    float* __restrict__ y1)
{
    int gid = blockIdx.x * 256 + threadIdx.x;
    int px  = gid & 4095;
    int co  = (gid >> 12) & 31;
    int img = gid >> 17;
    const float* xin = (img < 4) ? (x1 + (size_t)img * NPX)
                                 : (x2 + (size_t)(img - 4) * NPX);
    int r = px >> 6, c = px & 63;
    float acc = bias[co];
#pragma unroll
    for (int dy = 0; dy < 3; ++dy) {
        int rr = r + dy - 1;
        if (rr < 0 || rr > 63) continue;
#pragma unroll
        for (int dx = 0; dx < 3; ++dx) {
            int cc = c + dx - 1;
            if (cc < 0 || cc > 63) continue;
            acc = fmaf(w[co * 9 + dy * 3 + dx], xin[rr * 64 + cc], acc);
        }
    }
    y1[(size_t)img * 32 * NPX + (size_t)co * NPX + px] = acc;
}

// ---------------------------------------------------------------------------
// wtrans: wT[(ci*9+tap)*CO + co] = w[co][ci][tap]  (conv2 only)
// ---------------------------------------------------------------------------
__global__ __launch_bounds__(256) void wtrans_k(
    const float* __restrict__ w, float* __restrict__ wT,
    int CI9, int CO, int total)
{
    int gid = blockIdx.x * 256 + threadIdx.x;
    if (gid >= total) return;
    int k = gid / CO, co = gid - k * CO;
    wT[gid] = w[(size_t)co * CI9 + k];
}

// ---------------------------------------------------------------------------
// convg: conv2 (32->64), register-tile implicit GEMM (proven round 3).
// ---------------------------------------------------------------------------
template <int CI>
__global__ __launch_bounds__(256) void convg_k(
    const float* __restrict__ in,
    const float* __restrict__ wT,
    const float* __restrict__ bias,
    float* __restrict__ outA, float* __restrict__ outB,
    int strideA, int strideB, int COT)
{
    constexpr int CIC = 16;
    __shared__ __align__(16) float in_lds[CIC * 6 * 64];
    __shared__ __align__(16) float w_lds[CIC * 9 * 64];

    const int r0  = blockIdx.x * 4;
    const int img = blockIdx.y;
    const int cob = blockIdx.z * 64;
    const int tid = threadIdx.x;
    const int co4 = (tid & 15) * 4;
    const int pxg = tid >> 4;
    const int row_l = pxg >> 2;
    const int c0 = (pxg & 3) * 16;

    const float* ib = in + (size_t)img * CI * NPX;

    float acc[4][16];
#pragma unroll
    for (int e = 0; e < 4; ++e) {
        float bv = bias[cob + co4 + e];
#pragma unroll
        for (int p = 0; p < 16; ++p) acc[e][p] = bv;
    }

    for (int cic = 0; cic < CI; cic += CIC) {
        __syncthreads();
#pragma unroll
        for (int t = 0; t < 6; ++t) {
            int f = tid + t * 256;
            int ci = f / 96, rem = f - ci * 96;
            int dyr = rem >> 4, c4 = rem & 15;
            int gr = r0 + dyr - 1;
            float4 v = make_float4(0.f, 0.f, 0.f, 0.f);
            if (gr >= 0 && gr < 64)
                v = *(const float4*)&ib[(size_t)(cic + ci) * NPX + gr * 64 + c4 * 4];
            *(float4*)&in_lds[(ci * 6 + dyr) * 64 + c4 * 4] = v;
        }
#pragma unroll
        for (int t = 0; t < 9; ++t) {
            int f = tid + t * 256;
            int k = f >> 4, c4 = f & 15;
            *(float4*)&w_lds[k * 64 + c4 * 4] =
                *(const float4*)&wT[(size_t)(cic * 9 + k) * COT + cob + c4 * 4];
        }
        __syncthreads();

        for (int ci = 0; ci < CIC; ++ci) {
#pragma unroll
            for (int dy = 0; dy < 3; ++dy) {
                const float* rp = &in_lds[(ci * 6 + row_l + dy) * 64 + c0];
                float v[18];
                float left  = rp[(c0 == 0)  ? 0 : -1];
                float right = rp[(c0 == 48) ? 0 : 16];
                v[0]  = (c0 == 0)  ? 0.f : left;
                *(float4*)&v[1]  = *(const float4*)&rp[0];
                *(float4*)&v[5]  = *(const float4*)&rp[4];
                *(float4*)&v[9]  = *(const float4*)&rp[8];
                *(float4*)&v[13] = *(const float4*)&rp[12];
                v[17] = (c0 == 48) ? 0.f : right;
                const float* wp = &w_lds[(ci * 9 + dy * 3) * 64 + co4];
                float wv[3][4];
                *(float4*)&wv[0][0] = *(const float4*)&wp[0];
                *(float4*)&wv[1][0] = *(const float4*)&wp[64];
                *(float4*)&wv[2][0] = *(const float4*)&wp[128];
#pragma unroll
                for (int dx = 0; dx < 3; ++dx)
#pragma unroll
                    for (int e = 0; e < 4; ++e)
#pragma unroll
                        for (int p = 0; p < 16; ++p)
                            acc[e][p] = fmaf(wv[dx][e], v[p + dx], acc[e][p]);
            }
        }
    }

    float* dst = (img < 4) ? (outA + (size_t)img * strideA)
                           : (outB + (size_t)(img - 4) * strideB);
    dst += (size_t)(cob + co4) * NPX + (r0 + row_l) * 64 + c0;
#pragma unroll
    for (int e = 0; e < 4; ++e)
#pragma unroll
        for (int q = 0; q < 4; ++q)
            *(float4*)&dst[(size_t)e * NPX + q * 4] = *(float4*)&acc[e][q * 4];
}

// ---------------------------------------------------------------------------
// wprep: w3 [256co][64ci][9tap] -> frag-contiguous bf16 h/l buffer.
// ---------------------------------------------------------------------------
__global__ __launch_bounds__(256) void wprep_k(
    const float* __restrict__ w3, unsigned short* __restrict__ w3f)
{
    int i = blockIdx.x * 256 + threadIdx.x;
    if (i >= 147456) return;
    int tap = i % 9;  int t2 = i / 9;
    int ci = t2 & 63; int co = t2 >> 6;
    float v = w3[(size_t)(co * 64 + ci) * 9 + tap];
    unsigned short hi = f2bf_rne(v);
    unsigned short lo = f2bf_rne(v - bf2f(hi));
    int cg = co >> 7, wm = (co >> 6) & 1, mf = (co >> 4) & 3, l15 = co & 15;
    int ch = ci >> 5, q = (ci >> 3) & 3, e = ci & 7;
    int lane = q * 16 + l15;
    size_t o = (size_t)(cg * 2 + wm) * 73728 + tap * 8192 + ch * 4096
             + mf * 512 + lane * 8 + e;
    w3f[o] = hi;
    w3f[o + 2048] = lo;
}

// ---------------------------------------------------------------------------
// y2prep: y2 [8][64ci][4096px] fp32 -> h/l [8][66 rows][64px][64ci] bf16.
// ---------------------------------------------------------------------------
__global__ __launch_bounds__(256) void y2prep_k(
    const float* __restrict__ y2,
    unsigned short* __restrict__ h, unsigned short* __restrict__ l)
{
    const int rg = blockIdx.x;   // 0..65
    const int img = blockIdx.y;
    const int tid = threadIdx.x;
    const size_t base = ((size_t)img * 66 + rg) * 4096;
    if (rg == 0 || rg == 65) {
#pragma unroll
        for (int t = 0; t < 16; ++t) {
            h[base + tid + t * 256] = 0;
            l[base + tid + t * 256] = 0;
        }
        return;
    }
    __shared__ float T[64][65];
    const int row = rg - 1;
#pragma unroll
    for (int t = 0; t < 16; ++t) {
        int ii = tid + t * 256;
        int ci = ii >> 6, col = ii & 63;
        T[ci][col] = y2[(size_t)img * 262144 + (size_t)ci * NPX + row * 64 + col];
    }
    __syncthreads();
#pragma unroll
    for (int t = 0; t < 16; ++t) {
        int ii = tid + t * 256;
        int ci = ii & 63, px = ii >> 6;
        float v = T[ci][px];
        unsigned short hi = f2bf_rne(v);
        h[base + px * 64 + ci] = hi;
        l[base + px * 64 + ci] = f2bf_rne(v - bf2f(hi));
    }
}

// ---------------------------------------------------------------------------
// conv3m: conv3 (64->256) as 9-tap shifted MFMA GEMM (proven round 5).
// ---------------------------------------------------------------------------
__global__ __launch_bounds__(512, 2) void conv3m_k(
    const unsigned short* __restrict__ y2ph,
    const unsigned short* __restrict__ y2pl,
    const unsigned short* __restrict__ w3f,
    const float* __restrict__ b3,
    float* __restrict__ out, float* __restrict__ f2)
{
    __shared__ unsigned short xlds[49152];
    const int pxg = blockIdx.x;
    const int img = blockIdx.y;
    const int cg  = blockIdx.z;
    const int tid = threadIdx.x;
    const int lane = tid & 63;
    const int wid = tid >> 6;
    const int wm = wid >> 2, wn = wid & 3;
    const int q16 = lane >> 4, l15 = lane & 15;
    const int r0 = pxg * 4;
    const int px0 = pxg * 256;
    const int cob = cg * 128;

    const unsigned short* yh = y2ph + (size_t)img * 270336;
    const unsigned short* yl = y2pl + (size_t)img * 270336;
#pragma unroll
    for (int it = 0; it < 12; ++it) {
        int dbase = it * 8192 + wid * 1024;
        int d = dbase + lane * 16;
        int s = d >= 49152;
        int r = d - (s ? 49152 : 0);
        int pxl = r >> 7;
        int kbs = (r >> 4) & 7;
        int kb  = kbs ^ (pxl & 7);
        int rg  = r0 + (pxl >> 6);
        int col = pxl & 63;
        const unsigned short* src = (s ? yl : yh) + ((rg << 6) + col) * 64 + kb * 8;
        GLL(src, (char*)xlds + dbase);
    }

    const unsigned short* wbase = w3f + (size_t)(cg * 2 + wm) * 73728 + lane * 8;
    bf16x8 awh[2][4], awl[2][4];
#pragma unroll
    for (int mf = 0; mf < 4; ++mf) {
        awh[0][mf] = *(const bf16x8*)(wbase + mf * 512);
        awl[0][mf] = *(const bf16x8*)(wbase + 2048 + mf * 512);
    }

    f32x4 acc[4][4];
#pragma unroll
    for (int mf = 0; mf < 4; ++mf) {
        float bv[4];
#pragma unroll
        for (int r = 0; r < 4; ++r)
            bv[r] = b3[cob + wm * 64 + mf * 16 + q16 * 4 + r];
#pragma unroll
        for (int nf = 0; nf < 4; ++nf)
#pragma unroll
            for (int r = 0; r < 4; ++r) acc[mf][nf][r] = bv[r];
    }

    const int plb = wn * 64 + 64 + l15;
    const int key_m = (lane + 7) & 7;
    const int key_0 = lane & 7;
    const int key_p = (lane + 1) & 7;
    const bf16x8 z8 = {0, 0, 0, 0, 0, 0, 0, 0};

    __syncthreads();

#pragma unroll
    for (int ch = 0; ch < 2; ++ch) {
#pragma unroll
        for (int tap = 0; tap < 9; ++tap) {
            const int st = ch * 9 + tap;
            const int cur = st & 1;
            if (st < 17) {
                const int nst = st + 1;
                const int nch = nst / 9, ntap = nst % 9;
#pragma unroll
                for (int mf = 0; mf < 4; ++mf) {
                    awh[cur ^ 1][mf] = *(const bf16x8*)(wbase + ntap * 8192 + nch * 4096 + mf * 512);
                    awl[cur ^ 1][mf] = *(const bf16x8*)(wbase + ntap * 8192 + nch * 4096 + 2048 + mf * 512);
                }
            }
            const int dy = tap / 3 - 1, dx = tap % 3 - 1;
            const int key = (dx < 0) ? key_m : ((dx > 0) ? key_p : key_0);
            bf16x8 bh[4], bl[4];
#pragma unroll
            for (int nf = 0; nf < 4; ++nf) {
                int row = plb + nf * 16 + dy * 64 + dx;
                row = row < 0 ? 0 : (row > 383 ? 383 : row);
                int kbs = (q16 + ch * 4) ^ key;
                int ba = row * 128 + kbs * 16;
                bh[nf] = *(const bf16x8*)((const char*)xlds + ba);
                bl[nf] = *(const bf16x8*)((const char*)xlds + ba + 49152);
                if (dx < 0 && nf == 0) {
                    bh[nf] = (l15 == 0) ? z8 : bh[nf];
                    bl[nf] = (l15 == 0) ? z8 : bl[nf];
                }
                if (dx > 0 && nf == 3) {
                    bh[nf] = (l15 == 15) ? z8 : bh[nf];
                    bl[nf] = (l15 == 15) ? z8 : bl[nf];
                }
            }
#pragma unroll
            for (int mf = 0; mf < 4; ++mf)
#pragma unroll
                for (int nf = 0; nf < 4; ++nf) {
                    f32x4 c = acc[mf][nf];
                    c = __builtin_amdgcn_mfma_f32_16x16x32_bf16(awh[cur][mf], bh[nf], c, 0, 0, 0);
                    c = __builtin_amdgcn_mfma_f32_16x16x32_bf16(awh[cur][mf], bl[nf], c, 0, 0, 0);
                    c = __builtin_amdgcn_mfma_f32_16x16x32_bf16(awl[cur][mf], bh[nf], c, 0, 0, 0);
                    acc[mf][nf] = c;
                }
        }
    }

    float* dst = (img < 4) ? out + (size_t)img * 512 * NPX
                           : f2  + (size_t)(img - 4) * 256 * NPX;
#pragma unroll
    for (int mf = 0; mf < 4; ++mf)
#pragma unroll
        for (int nf = 0; nf < 4; ++nf)
#pragma unroll
            for (int r = 0; r < 4; ++r) {
                int co = cob + wm * 64 + mf * 16 + q16 * 4 + r;
                int px = px0 + wn * 64 + nf * 16 + l15;
                dst[(size_t)co * NPX + px] = acc[mf][nf][r];
            }
}

// ---------------------------------------------------------------------------
// splitT: [256k][4096m] fp32 -> [4096m][256k] bf16 hi+lo (LDS transpose).
// ---------------------------------------------------------------------------
__global__ __launch_bounds__(256) void splitT_k(
    const float* __restrict__ src, size_t srcStride,
    unsigned short* __restrict__ dh, unsigned short* __restrict__ dl)
{
    __shared__ float T[64][65];
    const int m0 = blockIdx.x * 64, k0 = blockIdx.y * 64, b = blockIdx.z;
    const float* s = src + (size_t)b * srcStride;
    const int tid = threadIdx.x;
    const int cm = tid & 63, rk = tid >> 6;
#pragma unroll
    for (int t = 0; t < 16; ++t)
        T[rk + t * 4][cm] = s[(size_t)(k0 + rk + t * 4) * NPX + m0 + cm];
    __syncthreads();
    const int ck = tid & 63, rm = tid >> 6;
#pragma unroll
    for (int t = 0; t < 16; ++t) {
        int m = rm + t * 4;
        float v = T[ck][m];
        unsigned short hi = f2bf_rne(v);
        float lo = v - bf2f(hi);
        size_t o = ((size_t)b * NPX + m0 + m) * 256 + k0 + ck;
        dh[o] = hi;
        dl[o] = f2bf_rne(lo);
    }
}

// ---------------------------------------------------------------------------
// normB + minkey init
// ---------------------------------------------------------------------------
__global__ __launch_bounds__(256) void normb_k(
    const float* __restrict__ f2, float* __restrict__ normB,
    unsigned long long* __restrict__ minkey)
{
    int gid = blockIdx.x * 256 + threadIdx.x;
    int b = gid >> 12, j = gid & 4095;
    const float* p = f2 + (size_t)b * 256 * NPX + j;
    float s = 0.f;
#pragma unroll 8
    for (int c = 0; c < 256; ++c) {
        float v = p[(size_t)c * NPX];
        s = fmaf(v, v, s);
    }
    normB[gid] = s;
    minkey[gid] = ~0ull;
}

// ---------------------------------------------------------------------------
// gemm_argmin_mfma: cross = f1.f2^T via 3x bf16-split MFMA (hh+hl+lh),
// fused dist-key argmin. Tile 128i x 128j, BK=32, 4 waves 2x2.
// T4 counted-vmcnt schedule (this round's change): per iter —
//   STAGE(next)           // 8 GLL issued, stay IN FLIGHT across compute
//   s_waitcnt vmcnt(8)    // wait only the PREVIOUS iter's 8 loads
//   s_barrier             // all waves' current buffer staged
//   ds_read + MFMA        // compiler inserts lgkmcnt for reads
//   s_barrier             // reads done -> next iter may overwrite
// vs round-5's vmcnt(0)-drain inside __syncthreads (load latency on the
// critical path every iter; MfmaUtil was 30% with 3x pipe-time gap).
// Bank-conflict swizzle (both-sides XOR involution) unchanged, verified 0.
// ---------------------------------------------------------------------------
__global__ __launch_bounds__(256) void gemm_argmin_mfma_k(
    const unsigned short* __restrict__ f1h, const unsigned short* __restrict__ f1l,
    const unsigned short* __restrict__ f2h, const unsigned short* __restrict__ f2l,
    const float* __restrict__ normB,
    unsigned long long* __restrict__ minkey)
{
    __shared__ unsigned short lds[2][4][4096];   // [dbuf][Ah|Al|Bh|Bl], 64 KB
    const int b  = blockIdx.z;
    const int i0 = blockIdx.y * 128;
    const int j0 = blockIdx.x * 128;
    const int tid  = threadIdx.x;
    const int lane = tid & 63;
    const int w    = tid >> 6;
    const int wm   = w >> 1, wn = w & 1;

    const int srow  = w * 32 + (lane >> 2);
    const int skoff = (((lane & 3) ^ ((lane >> 3) & 3))) * 8;
    const unsigned short* pAh = f1h + ((size_t)b * NPX + i0 + srow) * 256 + skoff;
    const unsigned short* pAl = f1l + ((size_t)b * NPX + i0 + srow) * 256 + skoff;
    const unsigned short* pBh = f2h + ((size_t)b * NPX + j0 + srow) * 256 + skoff;
    const unsigned short* pBl = f2l + ((size_t)b * NPX + j0 + srow) * 256 + skoff;
    const unsigned short* pAh2 = pAh + 16 * 256;
    const unsigned short* pAl2 = pAl + 16 * 256;
    const unsigned short* pBh2 = pBh + 16 * 256;
    const unsigned short* pBl2 = pBl + 16 * 256;

#define STAGE(p) do { \
        GLL(pAh,  &lds[p][0][0] + w * 1024); GLL(pAh2, &lds[p][0][0] + w * 1024 + 512); \
        GLL(pAl,  &lds[p][1][0] + w * 1024); GLL(pAl2, &lds[p][1][0] + w * 1024 + 512); \
        GLL(pBh,  &lds[p][2][0] + w * 1024); GLL(pBh2, &lds[p][2][0] + w * 1024 + 512); \
        GLL(pBl,  &lds[p][3][0] + w * 1024); GLL(pBl2, &lds[p][3][0] + w * 1024 + 512); \
        pAh += 32; pAl += 32; pBh += 32; pBl += 32; \
        pAh2 += 32; pAl2 += 32; pBh2 += 32; pBl2 += 32; } while (0)

    const int r15 = lane & 15;
    const int swz = (r15 >> 1) & 3;
    const int aoff = (wm * 64 + r15) * 32 + (((lane >> 4) ^ swz)) * 8;
    const int boff = (wn * 64 + r15) * 32 + (((lane >> 4) ^ swz)) * 8;

    const f32x4 zero = {0.f, 0.f, 0.f, 0.f};
    f32x4 acc[4][4];
#pragma unroll
    for (int i = 0; i < 4; ++i)
#pragma unroll
        for (int j = 0; j < 4; ++j) acc[i][j] = zero;

    STAGE(0);                              // prologue: buffer 0 in flight

#pragma unroll
    for (int kb = 0; kb < 8; ++kb) {
        const int cur = kb & 1;
        if (kb < 7) {
            STAGE(cur ^ 1);                // next tile: loads stay in flight
            asm volatile("s_waitcnt vmcnt(8)" ::: "memory");  // prev 8 landed
        } else {
            asm volatile("s_waitcnt vmcnt(0)" ::: "memory");  // last tile
        }
        __builtin_amdgcn_s_barrier();      // all waves: buffer cur staged
        __builtin_amdgcn_sched_barrier(0);

        bf16x8 ah[4], al[4], bh[4], bl[4];
#pragma unroll
        for (int mf = 0; mf < 4; ++mf) {
            ah[mf] = *(const bf16x8*)&lds[cur][0][aoff + mf * 512];
            al[mf] = *(const bf16x8*)&lds[cur][1][aoff + mf * 512];
        }
#pragma unroll
        for (int nf = 0; nf < 4; ++nf) {
            bh[nf] = *(const bf16x8*)&lds[cur][2][boff + nf * 512];
            bl[nf] = *(const bf16x8*)&lds[cur][3][boff + nf * 512];
        }
#pragma unroll
        for (int mf = 0; mf < 4; ++mf)
#pragma unroll
            for (int nf = 0; nf < 4; ++nf) {
                f32x4 c = acc[mf][nf];
                c = __builtin_amdgcn_mfma_f32_16x16x32_bf16(ah[mf], bh[nf], c, 0, 0, 0);
                c = __builtin_amdgcn_mfma_f32_16x16x32_bf16(ah[mf], bl[nf], c, 0, 0, 0);
                c = __builtin_amdgcn_mfma_f32_16x16x32_bf16(al[mf], bh[nf], c, 0, 0, 0);
                acc[mf][nf] = c;
            }
        __builtin_amdgcn_s_barrier();      // reads of cur done -> overwrite ok
    }
#undef STAGE

    // epilogue: key = normB[j] - 2*cross packed with j; reduce over j-lanes
    float nbv[4];
    const float* nbp = normB + b * 4096 + j0 + wn * 64 + r15;
#pragma unroll
    for (int nf = 0; nf < 4; ++nf) nbv[nf] = nbp[nf * 16];
    const int jcol = j0 + wn * 64 + r15;

#pragma unroll
    for (int mf = 0; mf < 4; ++mf) {
#pragma unroll
        for (int reg = 0; reg < 4; ++reg) {
            unsigned long long kmin = ~0ull;
#pragma unroll
            for (int nf = 0; nf < 4; ++nf) {
                float d = fmaf(-2.f, acc[mf][nf][reg], nbv[nf]);
                unsigned u = __float_as_uint(d);
                u = (u & 0x80000000u) ? ~u : (u | 0x80000000u);
                unsigned long long key =
                    ((unsigned long long)u << 32) | (unsigned)(jcol + nf * 16);
                kmin = kmin < key ? kmin : key;
            }
#pragma unroll
            for (int s = 1; s < 16; s <<= 1) {
                unsigned long long o = __shfl_xor(kmin, s, 64);
                kmin = kmin < o ? kmin : o;
            }
            if (r15 == 0) {
                int i = i0 + wm * 64 + mf * 16 + (lane >> 4) * 4 + reg;
                atomicMin(&minkey[(size_t)b * 4096 + i], kmin);
            }
        }
    }
}

// ---------------------------------------------------------------------------
// gather
// ---------------------------------------------------------------------------
__global__ __launch_bounds__(256) void gather_k(
    const unsigned long long* __restrict__ minkey,
    const float* __restrict__ f2, float* __restrict__ out)
{
    int b  = blockIdx.y;
    int px = blockIdx.x * 256 + threadIdx.x;
    int idx = (int)(unsigned)(minkey[(size_t)b * 4096 + px] & 0xffffffffu);
    const float* src = f2 + (size_t)b * 256 * NPX;
    float* dst = out + (size_t)b * 512 * NPX + (size_t)256 * NPX + px;
#pragma unroll 4
    for (int c = 0; c < 256; ++c)
        dst[(size_t)c * NPX] = src[(size_t)c * NPX + idx];
}

// ---------------------------------------------------------------------------
extern "C" void kernel_launch(void* const* d_in, const int* in_sizes, int n_in,
                              void* d_out, int out_size, void* d_ws, size_t ws_size,
                              hipStream_t stream)
{
    const float* x1 = (const float*)d_in[0];
    const float* x2 = (const float*)d_in[1];
    const float* w1 = (const float*)d_in[2];
    const float* b1 = (const float*)d_in[3];
    const float* w2 = (const float*)d_in[4];
    const float* b2 = (const float*)d_in[5];
    const float* w3 = (const float*)d_in[6];
    const float* b3 = (const float*)d_in[7];
    float* out = (float*)d_out;
    char* ws = (char*)d_ws;

    // ws layout (bytes); high-water ~55.7 MB
    float* y1 = (float*)(ws);                               // dead after conv2
    float* y2 = (float*)(ws + 4194304);                     // dead after y2prep
    float* f2 = (float*)(ws + 12582912);                    // live to end
    float* normB = (float*)(ws + 29360128);
    unsigned long long* minkey = (unsigned long long*)(ws + 29425664);
    float* w2T = (float*)(ws + 29556736);
    unsigned short* w3f  = (unsigned short*)(ws + 29630464);   // 576 KB
    unsigned short* y2ph = (unsigned short*)(ws + 30220288);   // dead after conv3
    unsigned short* y2pl = (unsigned short*)(ws + 34545664);   // dead after conv3
    unsigned short* f1h  = (unsigned short*)(ws);              // overlays y1+y2
    unsigned short* f1l  = (unsigned short*)(ws + 30220288);   // overlays y2pre
    unsigned short* f2h  = (unsigned short*)(ws + 38871040);
    unsigned short* f2l  = (unsigned short*)(ws + 47259648);   // ends 55.65M

    wtrans_k<<<72, 256, 0, stream>>>(w2, w2T, 32 * 9, 64, 64 * 288);
    wprep_k<<<576, 256, 0, stream>>>(w3, w3f);

    conv1_k<<<4096, 256, 0, stream>>>(x1, x2, w1, b1, y1);

    convg_k<32><<<dim3(16, 8, 1), 256, 0, stream>>>(
        y1, w2T, b2, y2, y2 + (size_t)4 * 64 * NPX, 64 * NPX, 64 * NPX, 64);

    y2prep_k<<<dim3(66, 8), 256, 0, stream>>>(y2, y2ph, y2pl);

    conv3m_k<<<dim3(16, 8, 2), 512, 0, stream>>>(y2ph, y2pl, w3f, b3, out, f2);

    normb_k<<<64, 256, 0, stream>>>(f2, normB, minkey);

    splitT_k<<<dim3(64, 4, 4), 256, 0, stream>>>(out, (size_t)512 * NPX, f1h, f1l);
    splitT_k<<<dim3(64, 4, 4), 256, 0, stream>>>(f2,  (size_t)256 * NPX, f2h, f2l);

    gemm_argmin_mfma_k<<<dim3(32, 32, 4), 256, 0, stream>>>(
        f1h, f1l, f2h, f2l, normB, minkey);

    gather_k<<<dim3(16, 4), 256, 0, stream>>>(minkey, f2, out);
}